// Round 6
// baseline (12336.860 us; speedup 1.0000x reference)
//
#include <hip/hip_runtime.h>

// RnnGenerator: C=2048, 4-layer ReLU RNN, 512 autoregressive steps = 2048
// strictly serial GEMV stages + 3-layer MLP LengthProducer.
// Round-6: round-5 epoch-tagged dataflow, poll loads batched via INLINE ASM.
//  - Round-5 post-mortem: LLVM refuses to cluster relaxed atomic loads ->
//    each polled 8B load got its own vmcnt wait -> 8 serial ~700cyc MALL
//    misses per round = 5.9us/stage. Fix: one asm block issues all 8
//    global_load_dwordx2 ... sc1 back-to-back + ONE s_waitcnt vmcnt(0).
//    sc1 = device-scope load (same policy __hip_atomic_load(AGENT) emits),
//    so coherence semantics are identical to the passing round-5 kernel.
//  - Everything else unchanged: weights resident (l0-2 rows in VGPR/AGPR,
//    l3 in 128KB LDS), producers publish 8B {val|tag} with relaxed agent
//    stores (critical-chain value first), 256 WGs x 512 thr, 1 WG/CU.
// fp32 everywhere: states binarize to exactly {0,1}; bf16 would flip
// near-zero pre-activation signs (trajectory is chaotic to that).

#define C      2048
#define NB     256
#define NT     512
#define STEPS  512

typedef unsigned long long u64;

// ws layout in u64 units
#define U_INP   0            // inp[2][C]
#define U_HIDB  (2*C)        // hidb[2][4][C]
#define U_HRAW  (10*C)       // hraw[3][C]
#define U_LP    (13*C)       // lp[3][C]

__device__ __forceinline__ float wred(float v) {
#pragma unroll
  for (int off = 32; off > 0; off >>= 1) v += __shfl_down(v, off, 64);
  return v;
}

__device__ __forceinline__ u64 pack(float val, int tag) {
  return ((u64)(unsigned)tag << 32) | (u64)__float_as_uint(val);
}
__device__ __forceinline__ void pub(u64* p, float val, int tag) {
  __hip_atomic_store(p, pack(val, tag), __ATOMIC_RELAXED, __HIP_MEMORY_SCOPE_AGENT);
}
__device__ __forceinline__ u64 peek(u64* p) {
  return __hip_atomic_load(p, __ATOMIC_RELAXED, __HIP_MEMORY_SCOPE_AGENT);
}
__device__ __forceinline__ float val_of(u64 v) { return __uint_as_float((unsigned)v); }
__device__ __forceinline__ int   tag_of(u64 v) { return (int)(v >> 32); }

// 8 device-scope loads issued back-to-back, ONE vmcnt drain.
__device__ __forceinline__ void peek8(const u64* a, const u64* b, u64 v[8]) {
  asm volatile(
    "global_load_dwordx2 %0, %8, off sc1\n\t"
    "global_load_dwordx2 %1, %8, off offset:8 sc1\n\t"
    "global_load_dwordx2 %2, %8, off offset:16 sc1\n\t"
    "global_load_dwordx2 %3, %8, off offset:24 sc1\n\t"
    "global_load_dwordx2 %4, %9, off sc1\n\t"
    "global_load_dwordx2 %5, %9, off offset:8 sc1\n\t"
    "global_load_dwordx2 %6, %9, off offset:16 sc1\n\t"
    "global_load_dwordx2 %7, %9, off offset:24 sc1\n\t"
    "s_waitcnt vmcnt(0)"
    : "=&v"(v[0]), "=&v"(v[1]), "=&v"(v[2]), "=&v"(v[3]),
      "=&v"(v[4]), "=&v"(v[5]), "=&v"(v[6]), "=&v"(v[7])
    : "v"(a), "v"(b)
    : "memory");
}

// 4-load variant for single-vector polls.
__device__ __forceinline__ void peek4(const u64* a, u64 v[4]) {
  asm volatile(
    "global_load_dwordx2 %0, %4, off sc1\n\t"
    "global_load_dwordx2 %1, %4, off offset:8 sc1\n\t"
    "global_load_dwordx2 %2, %4, off offset:16 sc1\n\t"
    "global_load_dwordx2 %3, %4, off offset:24 sc1\n\t"
    "s_waitcnt vmcnt(0)"
    : "=&v"(v[0]), "=&v"(v[1]), "=&v"(v[2]), "=&v"(v[3])
    : "v"(a)
    : "memory");
}

// Batched poll of two tagged vectors into LDS. Thread owns [4*tid..4*tid+3].
__device__ __forceinline__ void poll2(u64* __restrict__ A, int tagA,
                                      u64* __restrict__ B, int tagB,
                                      float* __restrict__ sa, float* __restrict__ sb,
                                      int tid) {
  const u64* a = A + 4 * tid;
  const u64* b = B + 4 * tid;
  u64 v[8];
  for (;;) {
    peek8(a, b, v);
    bool ok = (tag_of(v[0]) == tagA) & (tag_of(v[1]) == tagA)
            & (tag_of(v[2]) == tagA) & (tag_of(v[3]) == tagA)
            & (tag_of(v[4]) == tagB) & (tag_of(v[5]) == tagB)
            & (tag_of(v[6]) == tagB) & (tag_of(v[7]) == tagB);
    if (ok) break;
    __builtin_amdgcn_s_sleep(1);
  }
  float4 fa = { val_of(v[0]), val_of(v[1]), val_of(v[2]), val_of(v[3]) };
  float4 fb = { val_of(v[4]), val_of(v[5]), val_of(v[6]), val_of(v[7]) };
  ((float4*)sa)[tid] = fa;
  ((float4*)sb)[tid] = fb;
}

__device__ __forceinline__ void poll1(u64* __restrict__ A, int tagA,
                                      float* __restrict__ sa, int tid) {
  const u64* a = A + 4 * tid;
  u64 v[4];
  for (;;) {
    peek4(a, v);
    bool ok = (tag_of(v[0]) == tagA) & (tag_of(v[1]) == tagA)
            & (tag_of(v[2]) == tagA) & (tag_of(v[3]) == tagA);
    if (ok) break;
    __builtin_amdgcn_s_sleep(1);
  }
  float4 fa = { val_of(v[0]), val_of(v[1]), val_of(v[2]), val_of(v[3]) };
  ((float4*)sa)[tid] = fa;
}

__global__ void init_kernel(const float* __restrict__ x, u64* __restrict__ ws) {
  int i = blockIdx.x * blockDim.x + threadIdx.x;
  if (i < C) {
    ws[U_INP + i]          = pack(0.f, 0);    // inp(t=0) expects tag 0
    ws[U_HIDB + 0 * C + i] = pack(x[i], -3);  // hid_l(t=-1): tag l-3
    ws[U_HIDB + 1 * C + i] = pack(0.f, -2);
    ws[U_HIDB + 2 * C + i] = pack(0.f, -1);
    ws[U_HIDB + 3 * C + i] = pack(0.f, 0);
  }
}

__global__ __launch_bounds__(NT, 2) void rnn_persist(
    const float* __restrict__ x,
    const float* __restrict__ lp_w,  const float* __restrict__ lp_b,
    const float* __restrict__ lp_wout, const float* __restrict__ lp_bout,
    const float* __restrict__ w_ih,  const float* __restrict__ b_ih,
    const float* __restrict__ w_hh,  const float* __restrict__ b_hh,
    float* __restrict__ out, u64* __restrict__ ws)
{
  extern __shared__ float4 w3[];            // 8 waves x 2 mats x 512 f4 = 128 KB
  __shared__ __align__(16) float sh_a[C];   // 8 KB staged input vector
  __shared__ __align__(16) float sh_b[C];   // 8 KB staged hidden vector

  u64* inp  = ws + U_INP;
  u64* hidb = ws + U_HIDB;
  u64* hraw = ws + U_HRAW;
  u64* lp   = ws + U_LP;

  const int tid  = threadIdx.x;
  const int lane = tid & 63;
  const int wid  = tid >> 6;
  const int j    = blockIdx.x * 8 + wid;    // unit owned by this wave

  // ---------------- prime: layers 0-2 rows -> regs, layer 3 -> LDS --------
  const float4* WI = (const float4*)w_ih;
  const float4* WH = (const float4*)w_hh;
  float4 wir[3][8], whr[3][8];
#pragma unroll
  for (int l = 0; l < 3; ++l) {
    const size_t bi = (size_t)(l * C + j) * 512;
#pragma unroll
    for (int r = 0; r < 8; ++r) {
      wir[l][r] = WI[bi + r * 64 + lane];
      whr[l][r] = WH[bi + r * 64 + lane];
    }
  }
  {
    const size_t b3 = (size_t)(3 * C + j) * 512;
#pragma unroll
    for (int r = 0; r < 8; ++r) {
      w3[(wid * 2 + 0) * 512 + r * 64 + lane] = WI[b3 + r * 64 + lane];
      w3[(wid * 2 + 1) * 512 + r * 64 + lane] = WH[b3 + r * 64 + lane];
    }
  }
  float bias[4];
#pragma unroll
  for (int l = 0; l < 4; ++l) bias[l] = b_ih[l * C + j] + b_hh[l * C + j];
  __syncthreads();

  // ---------------- LengthProducer (dataflow) -----------------------------
  for (int s = 0; s < 3; ++s) {
    if (s == 0) ((float4*)sh_a)[tid] = ((const float4*)x)[tid];
    else        poll1(lp + (size_t)(s - 1) * C, s, sh_a, tid);
    __syncthreads();
    const float4* Wr  = (const float4*)(lp_w + ((size_t)s * C + j) * C);
    const float4* sa4 = (const float4*)sh_a;
    float a0 = 0, a1 = 0, a2 = 0, a3 = 0;
#pragma unroll
    for (int r = 0; r < 8; ++r) {
      float4 w = Wr[r * 64 + lane]; float4 h = sa4[r * 64 + lane];
      a0 = fmaf(w.x, h.x, a0); a1 = fmaf(w.y, h.y, a1);
      a2 = fmaf(w.z, h.z, a2); a3 = fmaf(w.w, h.w, a3);
    }
    float acc = wred((a0 + a1) + (a2 + a3));
    if (lane == 0) {
      float v = acc + lp_b[s * C + j];
      pub(&lp[(size_t)s * C + j], (v >= 0.f) ? v : 0.2f * v, s + 1);
    }
    __syncthreads();   // sh_a reuse protection
  }

  // LP head: block 0 wave 0 polls lp[2] (tag 3), batched via peek4.
  if (blockIdx.x == 0 && wid == 0) {
    float p = 0.f;
#pragma unroll
    for (int g = 0; g < 8; ++g) {
      // lane covers 64 groups of 4 contiguous elements: base = g*256 + lane*4
      const u64* a = &lp[2 * C + g * 256 + lane * 4];
      u64 v[4];
      for (;;) {
        peek4(a, v);
        bool ok = (tag_of(v[0]) == 3) & (tag_of(v[1]) == 3)
                & (tag_of(v[2]) == 3) & (tag_of(v[3]) == 3);
        if (ok) break;
        __builtin_amdgcn_s_sleep(1);
      }
#pragma unroll
      for (int r = 0; r < 4; ++r)
        p = fmaf(lp_wout[g * 256 + lane * 4 + r], val_of(v[r]), p);
    }
    p = wred(p);
    if (lane == 0) {
      float l = fabsf(p + lp_bout[0]);
      out[(size_t)STEPS * C] = fminf(l, 0.9999f);
    }
  }

  // ---------------- 512 steps x 4 layers, pure dataflow -------------------
  for (int t = 0; t < STEPS; ++t) {
    const int p = t & 1;
#pragma unroll
    for (int l = 0; l < 4; ++l) {
      u64* A    = (l == 0) ? (inp + (size_t)p * C) : (hraw + (size_t)(l - 1) * C);
      int  tagA = (l == 0) ? (4 * t) : (4 * t + l);
      u64* B    = hidb + (size_t)(p * 4 + l) * C;
      int  tagB = 4 * t + l - 3;
      poll2(A, tagA, B, tagB, sh_a, sh_b, tid);
      __syncthreads();

      const float4* sa4 = (const float4*)sh_a;
      const float4* sb4 = (const float4*)sh_b;
      float a0 = 0, a1 = 0, a2 = 0, a3 = 0;
      if (l < 3) {
#pragma unroll
        for (int r = 0; r < 8; ++r) {
          float4 h = sa4[r * 64 + lane]; float4 w = wir[l][r];
          a0 = fmaf(w.x, h.x, a0); a1 = fmaf(w.y, h.y, a1);
          a2 = fmaf(w.z, h.z, a2); a3 = fmaf(w.w, h.w, a3);
          float4 g = sb4[r * 64 + lane]; float4 v = whr[l][r];
          a0 = fmaf(v.x, g.x, a0); a1 = fmaf(v.y, g.y, a1);
          a2 = fmaf(v.z, g.z, a2); a3 = fmaf(v.w, g.w, a3);
        }
      } else {
#pragma unroll
        for (int r = 0; r < 8; ++r) {
          float4 h = sa4[r * 64 + lane]; float4 w = w3[(wid * 2 + 0) * 512 + r * 64 + lane];
          a0 = fmaf(w.x, h.x, a0); a1 = fmaf(w.y, h.y, a1);
          a2 = fmaf(w.z, h.z, a2); a3 = fmaf(w.w, h.w, a3);
          float4 g = sb4[r * 64 + lane]; float4 v = w3[(wid * 2 + 1) * 512 + r * 64 + lane];
          a0 = fmaf(v.x, g.x, a0); a1 = fmaf(v.y, g.y, a1);
          a2 = fmaf(v.z, g.z, a2); a3 = fmaf(v.w, g.w, a3);
        }
      }
      float acc = wred((a0 + a1) + (a2 + a3));

      if (lane == 0) {
        float pre = acc + bias[l];
        float h   = fmaxf(pre, 0.f);
        float bin = h / (h + 1e-12f);
        const int tg = 4 * t + l + 1;
        if (l < 3) {
          pub(&hraw[(size_t)l * C + j], h, tg);              // critical first
          pub(&hidb[(size_t)((p ^ 1) * 4 + l) * C + j], bin, tg);
        } else {
          pub(&inp[(size_t)(p ^ 1) * C + j], bin, tg);       // critical first
          pub(&hidb[(size_t)((p ^ 1) * 4 + 3) * C + j], bin, tg);
          out[(size_t)t * C + j] = bin;
        }
      }
      __syncthreads();   // sh_a/sh_b reuse protection before next poll
    }
  }
}

extern "C" void kernel_launch(void* const* d_in, const int* in_sizes, int n_in,
                              void* d_out, int out_size, void* d_ws, size_t ws_size,
                              hipStream_t stream) {
  const float* x       = (const float*)d_in[0];
  const float* lp_w    = (const float*)d_in[1];
  const float* lp_b    = (const float*)d_in[2];
  const float* lp_wout = (const float*)d_in[3];
  const float* lp_bout = (const float*)d_in[4];
  const float* w_ih    = (const float*)d_in[5];
  const float* b_ih    = (const float*)d_in[6];
  const float* w_hh    = (const float*)d_in[7];
  const float* b_hh    = (const float*)d_in[8];
  float* out = (float*)d_out;
  u64*   ws  = (u64*)d_ws;

  hipLaunchKernelGGL(init_kernel, dim3(8), dim3(256), 0, stream, x, ws);
  hipLaunchKernelGGL(rnn_persist, dim3(NB), dim3(NT),
                     8 * 2 * 512 * sizeof(float4) /* 128 KB dyn LDS */, stream,
                     x, lp_w, lp_b, lp_wout, lp_bout,
                     w_ih, b_ih, w_hh, b_hh, out, ws);
}